// Round 4
// baseline (18977.400 us; speedup 1.0000x reference)
//
#include <hip/hip_runtime.h>
#include <math.h>

// ---------------------------------------------------------------------------
// NetGIN forward on MI355X — round 4: MFMA GEMM (bf16 2-term split, fp32 acc).
// Activations stored RAW (pre-BN) fp16; S = {scale[128], shift[128]} fp32
// applies BN+ReLU on read. GEMM: A (bn-relu'd, fp32) split to bf16 hi/lo in
// LDS; W pre-transposed+split once into ws; 3 MFMA products per tile give
// ~2^-18 relative GEMM-input error (negligible vs fp16 store noise 2^-12).
// Epilogue: +bias, round fp16, store, BN stats from rounded values.
// ---------------------------------------------------------------------------

#define DEV_INLINE __device__ __forceinline__
typedef unsigned short u16;

union F16U { _Float16 h; u16 u; };
DEV_INLINE float h2f(u16 v){ F16U t; t.u = v; return (float)t.h; }
DEV_INLINE u16 f2h(float f){ F16U t; t.h = (_Float16)f; return t.u; }
DEV_INLINE float bf2f(u16 h){ return __uint_as_float(((unsigned)h)<<16); }
DEV_INLINE u16 f2bf(float f){
  unsigned u = __float_as_uint(f);
  unsigned r = (u + 0x7FFFu + ((u>>16)&1u)) >> 16;
  return (u16)r;
}
DEV_INLINE float sigmoidf_(float x){ return 1.0f/(1.0f+expf(-x)); }
struct __align__(4) us2 { u16 x, y; };
struct __align__(8) us4 { u16 x, y, z, w; };

typedef __attribute__((ext_vector_type(8))) short s8v;   // 8 bf16 (4 VGPRs)
typedef __attribute__((ext_vector_type(4))) float f4v;   // 4 fp32 acc

// ---------------- utility ----------------
__global__ void zero_k(float* __restrict__ p, int n){
  int i = blockIdx.x*256 + threadIdx.x;
  if (i < n) p[i] = 0.f;
}

// ---------------- weight pre-transpose + bf16 split ----------------
// src: [count][K][128] fp32 row-major.  dst planes: [count][128][K] (n-major).
__global__ __launch_bounds__(256) void split_transpose(
  const float* __restrict__ src, u16* __restrict__ dh, u16* __restrict__ dl,
  int K, int count)
{
  int tot = count*K*128;
  for (int i = blockIdx.x*256 + threadIdx.x; i < tot; i += gridDim.x*256){
    int k = i % K;
    int n = (i / K) & 127;
    int c = i / (K*128);
    float w = src[(size_t)c*K*128 + (size_t)k*128 + n];
    u16 hi = f2bf(w);
    u16 lo = f2bf(w - bf2f(hi));
    dh[i] = hi; dl[i] = lo;
  }
}

// ---------------- CSR build ----------------
__global__ void count_deg(const int* __restrict__ dst, int* __restrict__ cnt, int E){
  int e = blockIdx.x*256 + threadIdx.x;
  if (e < E) atomicAdd(&cnt[dst[e]], 1);
}

__global__ void scan_excl(const int* __restrict__ cnt, int* __restrict__ offs, int N){
  const int* c = cnt + (size_t)blockIdx.x * N;
  int* o = offs + (size_t)blockIdx.x * (N+1);
  __shared__ int ps[1024];
  int t = threadIdx.x;
  int chunk = (N + 1023) >> 10;
  int lo = t*chunk, hi = min(lo+chunk, N);
  int s = 0;
  for (int i=lo;i<hi;++i) s += c[i];
  ps[t] = s; __syncthreads();
  for (int d=1; d<1024; d<<=1){
    int v = (t>=d) ? ps[t-d] : 0;
    __syncthreads();
    ps[t] += v;
    __syncthreads();
  }
  int pre = (t==0) ? 0 : ps[t-1];
  for (int i=lo;i<hi;++i){ o[i]=pre; pre += c[i]; }
  if (t==1023) o[N] = ps[1023];
}

__global__ void fill_csr(const int* __restrict__ src, const int* __restrict__ dst,
                         const int* __restrict__ offs, int* __restrict__ cur,
                         int* __restrict__ out, int E){
  int e = blockIdx.x*256 + threadIdx.x;
  if (e >= E) return;
  int d = dst[e];
  int pos = offs[d] + atomicAdd(&cur[d], 1);
  out[pos] = src[e];
}

__global__ void graph_offsets(const int* __restrict__ batch, int* __restrict__ goff, int N, int G){
  int g = blockIdx.x*blockDim.x + threadIdx.x;
  if (g > G) return;
  int lo=0, hi=N;
  while (lo<hi){ int mid=(lo+hi)>>1; if (batch[mid] < g) lo=mid+1; else hi=mid; }
  goff[g]=lo;
}

// ---------------- BN finalize ----------------
__global__ void bnfin(float* __restrict__ stats, const float* __restrict__ g,
                      const float* __restrict__ be, float* __restrict__ S, float invN){
  int c = threadIdx.x;   // 128
  float m = stats[c]*invN;
  float v = stats[128+c]*invN - m*m;
  float sc = g[c]*rsqrtf(v + 1e-5f);
  S[c] = sc;
  S[128+c] = be[c] - m*sc;
  stats[c] = 0.f; stats[128+c] = 0.f;
}

// ---------------- MFMA GEMM ----------------
// C(N,128) = bnrelu(A)(N,K) @ W(K,128) + bias;  K = npart*128.
// A parts fp16 N x 128; wt_hi/wt_lo: W^T split planes [128][K].
// Block: 256 thr (4 waves, 2Mx2N), tile 128x128, K-chunks of 64.
// Fragment layouts (mfma_f32_16x16x32_bf16):
//   A-op (=W^T): row n=lane&15, k = 8*(lane>>4)+j   (contiguous 8, 16B)
//   B-op (=X^T): col m=lane&15, k = 8*(lane>>4)+j
//   D (=C^T):    col m=lane&15, row n=(lane>>4)*4+reg   [verified m89/m91]
#define LDP 72   // padded LDS row stride (elems): 2-way bank conflicts only
__global__ __launch_bounds__(256) void gemm_mfma(
  const u16* __restrict__ A0, const u16* __restrict__ A1,
  const u16* __restrict__ A2, const u16* __restrict__ A3,
  const float* __restrict__ S0, const float* __restrict__ S1,
  const float* __restrict__ S2, const float* __restrict__ S3,
  const u16* __restrict__ wt_hi, const u16* __restrict__ wt_lo,
  const float* __restrict__ bias,
  u16* __restrict__ C, float* __restrict__ stats,
  int N, int npart)
{
  __shared__ u16 ldsb[4*128*LDP];            // Xh, Xl, Wh, Wl : 73.7 KB
  u16* Xh = ldsb;
  u16* Xl = ldsb + 128*LDP;
  u16* Wh = ldsb + 2*128*LDP;
  u16* Wl = ldsb + 3*128*LDP;

  const int t = threadIdx.x;
  const int lane = t & 63;
  const int wid = t >> 6;
  const int wrow = (wid >> 1) * 64;          // wave M offset in tile
  const int wcol = (wid & 1) * 64;           // wave N offset
  const int row0 = blockIdx.x * 128;
  const int K = npart << 7;
  const int nchunks = K >> 6;

  f4v acc[4][4];
  #pragma unroll
  for (int i=0;i<4;++i)
    #pragma unroll
    for (int j=0;j<4;++j) acc[i][j] = (f4v){0.f,0.f,0.f,0.f};

  const int srow = t >> 4;                   // 0..15 (staging row within pass)
  const int skk  = (t & 15) << 2;            // 0,4,...,60 (staging k quad)

  for (int chunk = 0; chunk < nchunks; ++chunk){
    if (chunk) __syncthreads();              // previous compute done before overwrite
    const int part = chunk >> 1;
    const int kpart = (chunk & 1) << 6;      // k offset within part (0/64)
    const u16* A = (part==0)?A0:(part==1)?A1:(part==2)?A2:A3;
    const float* S = (part==0)?S0:(part==1)?S1:(part==2)?S2:S3;

    // ---- stage X (bn+relu in fp32, split to bf16 hi/lo) ----
    #pragma unroll
    for (int p=0;p<8;++p){
      int r = p*16 + srow;
      int row = row0 + r;
      float v0=0.f,v1=0.f,v2=0.f,v3=0.f;
      if (row < N){
        us4 u = *(const us4*)(A + (size_t)row*128 + kpart + skk);
        v0=h2f(u.x); v1=h2f(u.y); v2=h2f(u.z); v3=h2f(u.w);
      }
      if (S){
        const float* sc = S + kpart + skk;
        const float* sh = sc + 128;
        v0 = fmaxf(fmaf(v0, sc[0], sh[0]), 0.f);
        v1 = fmaxf(fmaf(v1, sc[1], sh[1]), 0.f);
        v2 = fmaxf(fmaf(v2, sc[2], sh[2]), 0.f);
        v3 = fmaxf(fmaf(v3, sc[3], sh[3]), 0.f);
      }
      us4 hq, lq;
      hq.x = f2bf(v0); lq.x = f2bf(v0 - bf2f(hq.x));
      hq.y = f2bf(v1); lq.y = f2bf(v1 - bf2f(hq.y));
      hq.z = f2bf(v2); lq.z = f2bf(v2 - bf2f(hq.z));
      hq.w = f2bf(v3); lq.w = f2bf(v3 - bf2f(hq.w));
      *(us4*)(Xh + r*LDP + skk) = hq;
      *(us4*)(Xl + r*LDP + skk) = lq;
    }
    // ---- stage W^T (pre-split planes, straight copy) ----
    #pragma unroll
    for (int p=0;p<8;++p){
      int nr = p*16 + srow;
      size_t ga = (size_t)nr*K + (chunk<<6) + skk;
      *(us4*)(Wh + nr*LDP + skk) = *(const us4*)(wt_hi + ga);
      *(us4*)(Wl + nr*LDP + skk) = *(const us4*)(wt_lo + ga);
    }
    __syncthreads();

    // ---- compute: 2 K=32 steps ----
    #pragma unroll
    for (int ks=0; ks<2; ++ks){
      const int k0 = ks*32 + 8*(lane>>4);
      s8v wfh[4], wfl[4];
      #pragma unroll
      for (int nt=0;nt<4;++nt){
        int nr = wcol + nt*16 + (lane&15);
        wfh[nt] = *(const s8v*)(Wh + nr*LDP + k0);
        wfl[nt] = *(const s8v*)(Wl + nr*LDP + k0);
      }
      #pragma unroll
      for (int mt=0;mt<4;++mt){
        int mr = wrow + mt*16 + (lane&15);
        s8v xh = *(const s8v*)(Xh + mr*LDP + k0);
        s8v xl = *(const s8v*)(Xl + mr*LDP + k0);
        #pragma unroll
        for (int nt=0;nt<4;++nt){
          acc[mt][nt] = __builtin_amdgcn_mfma_f32_16x16x32_bf16(wfh[nt], xh, acc[mt][nt], 0,0,0);
          acc[mt][nt] = __builtin_amdgcn_mfma_f32_16x16x32_bf16(wfl[nt], xh, acc[mt][nt], 0,0,0);
          acc[mt][nt] = __builtin_amdgcn_mfma_f32_16x16x32_bf16(wfh[nt], xl, acc[mt][nt], 0,0,0);
        }
      }
    }
  }

  // ---- epilogue: +bias, fp16 round, store, BN stats ----
  #pragma unroll
  for (int nt=0;nt<4;++nt){
    int n0 = wcol + nt*16 + (lane>>4)*4;     // 4 consecutive output cols
    float4 b4 = *(const float4*)(bias + n0);
    float s1x=0.f,s1y=0.f,s1z=0.f,s1w=0.f;
    float s2x=0.f,s2y=0.f,s2z=0.f,s2w=0.f;
    #pragma unroll
    for (int mt=0;mt<4;++mt){
      int m = row0 + wrow + mt*16 + (lane&15);
      if (m < N){
        us4 o;
        o.x = f2h(acc[mt][nt][0] + b4.x);
        o.y = f2h(acc[mt][nt][1] + b4.y);
        o.z = f2h(acc[mt][nt][2] + b4.z);
        o.w = f2h(acc[mt][nt][3] + b4.w);
        *(us4*)(C + (size_t)m*128 + n0) = o;
        float r0=h2f(o.x), r1=h2f(o.y), r2=h2f(o.z), r3=h2f(o.w);
        s1x+=r0; s1y+=r1; s1z+=r2; s1w+=r3;
        s2x+=r0*r0; s2y+=r1*r1; s2z+=r2*r2; s2w+=r3*r3;
      }
    }
    // reduce over m (lane&15) within each 16-lane group
    #pragma unroll
    for (int off=1; off<16; off<<=1){
      s1x += __shfl_xor(s1x, off, 64); s1y += __shfl_xor(s1y, off, 64);
      s1z += __shfl_xor(s1z, off, 64); s1w += __shfl_xor(s1w, off, 64);
      s2x += __shfl_xor(s2x, off, 64); s2y += __shfl_xor(s2y, off, 64);
      s2z += __shfl_xor(s2z, off, 64); s2w += __shfl_xor(s2w, off, 64);
    }
    if ((lane & 15) == 0){
      atomicAdd(&stats[n0+0], s1x); atomicAdd(&stats[n0+1], s1y);
      atomicAdd(&stats[n0+2], s1z); atomicAdd(&stats[n0+3], s1w);
      atomicAdd(&stats[128+n0+0], s2x); atomicAdd(&stats[128+n0+1], s2y);
      atomicAdd(&stats[128+n0+2], s2z); atomicAdd(&stats[128+n0+3], s2w);
    }
  }
}

// ---------------- small-K encoder GEMM (fp32 inputs, K <= 26) ----------------
__global__ __launch_bounds__(256) void gemm_enc(
  const float* __restrict__ X0, int w0, const float* __restrict__ X1, int w1,
  const float* __restrict__ W, const float* __restrict__ bias,
  u16* __restrict__ C, float* __restrict__ stats, int N)
{
  __shared__ float Ws[26*128];
  __shared__ float red[256];
  int K = w0 + w1;
  int t = threadIdx.x;
  for (int i=t;i<K*128;i+=256) Ws[i] = W[i];
  __syncthreads();
  int c = t & 127, rh = t >> 7;
  float b = bias[c];
  float s1=0.f, s2=0.f;
  for (int r0 = blockIdx.x*2; r0 < N; r0 += gridDim.x*2){
    int r = r0 + rh;
    if (r < N){
      float acc = b;
      for (int k=0;k<w0;++k) acc = fmaf(X0[(size_t)r*w0+k], Ws[k*128+c], acc);
      for (int k=0;k<w1;++k) acc = fmaf(X1[(size_t)r*w1+k], Ws[(w0+k)*128+c], acc);
      u16 o = f2h(acc);
      C[(size_t)r*128+c] = o;
      float rv = h2f(o);
      s1 += rv; s2 += rv*rv;
    }
  }
  red[t] = s1; __syncthreads();
  if (t < 128) atomicAdd(&stats[t], red[t] + red[t+128]);
  __syncthreads();
  red[t] = s2; __syncthreads();
  if (t < 128) atomicAdd(&stats[128+t], red[t] + red[t+128]);
}

// ---------------- GIN aggregation ----------------
__global__ __launch_bounds__(256) void aggregate_hf(
  const u16* __restrict__ X, const float* __restrict__ S,
  const int* __restrict__ srcs, const int* __restrict__ offs,
  const float* __restrict__ geps, int gi, u16* __restrict__ Z, int N)
{
  int i = blockIdx.x*4 + (threadIdx.x>>6);
  int ln = threadIdx.x & 63;
  int c = ln*2;
  if (i >= N) return;
  float sca = S[c], sha = S[128+c];
  float scb = S[c+1], shb = S[128+c+1];
  float eps1 = 1.0f + geps[gi];
  us2 x0 = *(const us2*)(X + (size_t)i*128 + c);
  float acca = eps1 * fmaxf(fmaf(h2f(x0.x), sca, sha), 0.f);
  float accb = eps1 * fmaxf(fmaf(h2f(x0.y), scb, shb), 0.f);
  int e0 = offs[i], e1 = offs[i+1];
  for (int e=e0; e<e1; ++e){
    int s = srcs[e];
    us2 xv = *(const us2*)(X + (size_t)s*128 + c);
    acca += fmaxf(fmaf(h2f(xv.x), sca, sha), 0.f);
    accb += fmaxf(fmaf(h2f(xv.y), scb, shb), 0.f);
  }
  us2 o; o.x = f2h(acca); o.y = f2h(accb);
  *(us2*)(Z + (size_t)i*128 + c) = o;
}

// ---------------- Set2Set ----------------
__global__ __launch_bounds__(256) void lstm_step(
  float* __restrict__ q_star, float* __restrict__ h, float* __restrict__ cst,
  const float* __restrict__ Wih, const float* __restrict__ Whh,
  const float* __restrict__ bih, const float* __restrict__ bhh, int G)
{
  __shared__ float q[256], hh[128], z[512];
  int t = threadIdx.x;
  for (int g = blockIdx.x; g < G; g += gridDim.x){
    q[t] = q_star[(size_t)g*256 + t];
    if (t < 128) hh[t] = h[(size_t)g*128 + t];
    __syncthreads();
    #pragma unroll
    for (int p=0;p<2;++p){
      int j = t + 256*p;
      float acc = bih[j] + bhh[j];
      const float* wi = Wih + (size_t)j*256;
      const float* wh = Whh + (size_t)j*128;
      for (int k=0;k<256;++k) acc = fmaf(q[k], wi[k], acc);
      for (int k=0;k<128;++k) acc = fmaf(hh[k], wh[k], acc);
      z[j] = acc;
    }
    __syncthreads();
    if (t < 128){
      float i_ = z[t], f_ = z[128+t], g_ = z[256+t], o_ = z[384+t];
      float cc = sigmoidf_(f_)*cst[(size_t)g*128+t] + sigmoidf_(i_)*tanhf(g_);
      float hn = sigmoidf_(o_)*tanhf(cc);
      cst[(size_t)g*128+t] = cc;
      h[(size_t)g*128+t]  = hn;
      q_star[(size_t)g*256+t] = hn;
    }
    __syncthreads();
  }
}

__global__ __launch_bounds__(256) void dot_h_hf(
  const u16* __restrict__ X, const float* __restrict__ S,
  const float* __restrict__ h, const int* __restrict__ batch,
  float* __restrict__ e, int N)
{
  int wv = threadIdx.x >> 6, ln = threadIdx.x & 63;
  int i = blockIdx.x*4 + wv;
  if (i >= N) return;
  int g = batch[i];
  int c = ln*2;
  us2 x2 = *(const us2*)(X + (size_t)i*128 + c);
  float2 h2 = *(const float2*)(h + (size_t)g*128 + c);
  float xa = fmaxf(fmaf(h2f(x2.x), S[c],   S[128+c]),   0.f);
  float xb = fmaxf(fmaf(h2f(x2.y), S[c+1], S[128+c+1]), 0.f);
  float p = xa*h2.x + xb*h2.y;
  #pragma unroll
  for (int off=32; off; off>>=1) p += __shfl_down(p, off, 64);
  if (ln==0) e[i] = p;
}

__global__ __launch_bounds__(256) void seg_reduce(
  const float* __restrict__ e, const int* __restrict__ goff,
  float* __restrict__ emax, float* __restrict__ invden, int G)
{
  int g = blockIdx.x;
  int lo = goff[g], hi = goff[g+1];
  int t = threadIdx.x;
  __shared__ float red[256];
  float m = -3.4e38f;
  for (int i=lo+t; i<hi; i+=256) m = fmaxf(m, e[i]);
  red[t] = m; __syncthreads();
  for (int d=128; d; d>>=1){ if (t<d) red[t] = fmaxf(red[t], red[t+d]); __syncthreads(); }
  m = red[0]; __syncthreads();
  float s = 0.f;
  for (int i=lo+t; i<hi; i+=256) s += expf(e[i]-m);
  red[t] = s; __syncthreads();
  for (int d=128; d; d>>=1){ if (t<d) red[t] += red[t+d]; __syncthreads(); }
  if (t==0){
    emax[g] = m;
    invden[g] = (hi>lo && red[0]>0.f) ? 1.f/red[0] : 0.f;
  }
}

__global__ __launch_bounds__(128) void r_kernel_hf(
  const u16* __restrict__ X, const float* __restrict__ S,
  const float* __restrict__ e, const int* __restrict__ goff,
  const float* __restrict__ emax, const float* __restrict__ invden,
  float* __restrict__ q_star, int G)
{
  int g = blockIdx.x, c = threadIdx.x;
  int lo = goff[g], hi = goff[g+1];
  float m = emax[g], inv = invden[g];
  float sc = S[c], sh = S[128+c];
  float r = 0.f;
  for (int i=lo; i<hi; ++i){
    float w = expf(e[i]-m);
    r = fmaf(w, fmaxf(fmaf(h2f(X[(size_t)i*128+c]), sc, sh), 0.f), r);
  }
  q_star[(size_t)g*256 + 128 + c] = r*inv;
}

__global__ __launch_bounds__(128) void final_k(
  const float* __restrict__ q_star, const float* __restrict__ fc1W,
  const float* __restrict__ fc1b, const float* __restrict__ fc4W,
  const float* __restrict__ fc4b, float* __restrict__ out, int G)
{
  __shared__ float q[256];
  __shared__ float h1[128];
  int g = blockIdx.x, t = threadIdx.x;
  q[t]     = q_star[(size_t)g*256 + t];
  q[128+t] = q_star[(size_t)g*256 + 128 + t];
  __syncthreads();
  float acc = fc1b[t];
  for (int k=0;k<256;++k) acc = fmaf(q[k], fc1W[(size_t)k*128+t], acc);
  h1[t] = fmaxf(acc, 0.f);
  __syncthreads();
  if (t < 12){
    float o = fc4b[t];
    for (int d=0; d<128; ++d) o = fmaf(h1[d], fc4W[(size_t)d*12+t], o);
    out[(size_t)g*12+t] = o;
  }
}

// ---------------------------------------------------------------------------
extern "C" void kernel_launch(void* const* d_in, const int* in_sizes, int n_in,
                              void* d_out, int out_size, void* d_ws, size_t ws_size,
                              hipStream_t stream)
{
  (void)n_in; (void)ws_size;
  const int N = in_sizes[0] / 3;
  const int E = in_sizes[62] / 2;
  const int G = out_size / 12;

  auto P = [&](int i){ return (const float*)d_in[i]; };
  const float* gb1 = P(38); const float* gg1 = P(39); const float* gbe1 = P(40);
  const float* gb2 = P(42); const float* gg2 = P(43); const float* gbe2 = P(44);
  const float* geps = P(45);
  const float* mb1 = P(47); const float* mg1 = P(48); const float* mbe1 = P(49);
  const float* mb2 = P(51); const float* mg2 = P(52); const float* mbe2 = P(53);
  const int* ei[4] = {(const int*)d_in[62], (const int*)d_in[63],
                      (const int*)d_in[64], (const int*)d_in[65]};
  const int* batch = (const int*)d_in[66];

  char* ws = (char*)d_ws;
  size_t off = 0;
  auto alloc = [&](size_t bytes)->char*{
    char* p = ws + off;
    off = (off + bytes + 255) & ~(size_t)255;
    return p;
  };
  u16* X = (u16*)alloc((size_t)N*128*2);              // also the MLP intermediate
  u16* Z[4]; for (int k=0;k<4;++k) Z[k] = (u16*)alloc((size_t)N*128*2);
  float* ebuf  = (float*)alloc((size_t)N*4);
  float* stats = (float*)alloc(256*4);
  float* Sb    = (float*)alloc(6*256*4);
  int* offs4 = (int*)alloc((size_t)4*(N+1)*4);
  int* srcs4 = (int*)alloc((size_t)4*E*4);
  int* cnt4  = (int*)alloc((size_t)4*N*4);
  int* goff  = (int*)alloc((size_t)(G+1)*4);
  float* qstar = (float*)alloc((size_t)G*256*4);
  float* hbuf  = (float*)alloc((size_t)G*128*4);
  float* cbuf  = (float*)alloc((size_t)G*128*4);
  float* emax  = (float*)alloc((size_t)G*4);
  float* invden= (float*)alloc((size_t)G*4);
  // W^T split planes. elems per plane (see offsets below): 1392640
  const size_t WT_ELEMS = 1392640;
  u16* WTh = (u16*)alloc(WT_ELEMS*2);
  u16* WTl = (u16*)alloc(WT_ELEMS*2);

  // W^T plane offsets (elems)
  const size_t oEnc0=0, oEnc1=16384, oEnc2=32768, oM0W1=49152, oM0W2=98304;
  const size_t oGW1=114688, oGW2=507904, oMW1=901120, oMW2=1294336;

  const float invN = 1.0f / (float)N;
  const int ST = 0, SX = 1, SZ0 = 2;
  auto Sl = [&](int i){ return Sb + (size_t)i*256; };

  // ---- weight preprocessing (transpose + bf16 split), every launch ----
  auto prep = [&](const float* src, size_t o, int K, int count){
    int tot = count*K*128;
    split_transpose<<<(tot+255)/256,256,0,stream>>>(src, WTh+o, WTl+o, K, count);
  };
  prep(P(9),  oEnc0, 128, 1);
  prep(P(17), oEnc1, 128, 1);
  prep(P(25), oEnc2, 128, 1);
  prep(P(29), oM0W1, 384, 1);
  prep(P(33), oM0W2, 128, 1);
  prep(P(37), oGW1,  128, 24);
  prep(P(41), oGW2,  128, 24);
  prep(P(46), oMW1,  512, 6);
  prep(P(50), oMW2,  128, 6);

  // ---- CSR build ----
  int zgrid = (4*N + 255)/256;
  zero_k<<<zgrid,256,0,stream>>>((float*)cnt4, 4*N);
  int egrid = (E + 255)/256;
  for (int l=0;l<4;++l)
    count_deg<<<egrid,256,0,stream>>>(ei[l]+E, cnt4 + (size_t)l*N, E);
  scan_excl<<<4,1024,0,stream>>>(cnt4, offs4, N);
  zero_k<<<zgrid,256,0,stream>>>((float*)cnt4, 4*N);
  for (int l=0;l<4;++l)
    fill_csr<<<egrid,256,0,stream>>>(ei[l], ei[l]+E, offs4 + (size_t)l*(N+1),
                                     cnt4 + (size_t)l*N, srcs4 + (size_t)l*E, E);
  graph_offsets<<<(G+1+255)/256,256,0,stream>>>(batch, goff, N, G);
  zero_k<<<1,256,0,stream>>>(stats, 256);

  int ggrid = (N + 127)/128;
  auto run_bnfin = [&](const float* g, const float* be, float* S){
    bnfin<<<1,128,0,stream>>>(stats, g, be, S, invN);
  };
  auto run_gemm1 = [&](const u16* A, const float* S, size_t wo, const float* b, u16* Cc){
    gemm_mfma<<<ggrid,256,0,stream>>>(A,nullptr,nullptr,nullptr, S,nullptr,nullptr,nullptr,
                                      WTh+wo, WTl+wo, b, Cc, stats, N, 1);
  };

  // ---- encoders (X doubles as the intermediate T) ----
  gemm_enc<<<1024,256,0,stream>>>(P(0),3, nullptr,0, P(5), P(6), X, stats, N);
  run_bnfin(P(7), P(8), Sl(ST));
  run_gemm1(X, Sl(ST), oEnc0, P(10), Z[0]);
  run_bnfin(P(11), P(12), Sl(SZ0+0));

  gemm_enc<<<1024,256,0,stream>>>(P(1),13, P(2),13, P(13), P(14), X, stats, N);
  run_bnfin(P(15), P(16), Sl(ST));
  run_gemm1(X, Sl(ST), oEnc1, P(18), Z[1]);
  run_bnfin(P(19), P(20), Sl(SZ0+1));

  gemm_enc<<<1024,256,0,stream>>>(P(3),4, P(4),1, P(21), P(22), X, stats, N);
  run_bnfin(P(23), P(24), Sl(ST));
  run_gemm1(X, Sl(ST), oEnc2, P(26), Z[2]);
  run_bnfin(P(27), P(28), Sl(SZ0+2));

  // m0: concat [nl, na, ea] = Z0,Z1,Z2  (K=384)
  gemm_mfma<<<ggrid,256,0,stream>>>(Z[0],Z[1],Z[2],nullptr,
                                    Sl(SZ0+0),Sl(SZ0+1),Sl(SZ0+2),nullptr,
                                    WTh+oM0W1, WTl+oM0W1, P(30), X, stats, N, 3);
  run_bnfin(P(31), P(32), Sl(ST));
  run_gemm1(X, Sl(ST), oM0W2, P(34), X);        // in-place (row-exclusive blocks)
  run_bnfin(P(35), P(36), Sl(SX));

  // ---- 6 GIN layers ----
  int agrid = (N + 3)/4;
  for (int L=0; L<6; ++L){
    for (int k=0;k<4;++k){
      int gi = 4*L + k;
      aggregate_hf<<<agrid,256,0,stream>>>(X, Sl(SX), srcs4 + (size_t)k*E,
                                           offs4 + (size_t)k*(N+1), geps, gi, Z[k], N);
    }
    for (int k=0;k<4;++k){
      int gi = 4*L + k;
      run_gemm1(Z[k], nullptr, oGW1 + (size_t)gi*16384, gb1 + (size_t)gi*128, X);
      run_bnfin(gg1 + (size_t)gi*128, gbe1 + (size_t)gi*128, Sl(ST));
      run_gemm1(X, Sl(ST), oGW2 + (size_t)gi*16384, gb2 + (size_t)gi*128, Z[k]);
      run_bnfin(gg2 + (size_t)gi*128, gbe2 + (size_t)gi*128, Sl(SZ0+k));
    }
    // fusion: concat [x1, x3, x2, x4] = Z0, Z2, Z1, Z3  (K=512)
    gemm_mfma<<<ggrid,256,0,stream>>>(Z[0],Z[2],Z[1],Z[3],
                                      Sl(SZ0+0),Sl(SZ0+2),Sl(SZ0+1),Sl(SZ0+3),
                                      WTh+oMW1+(size_t)L*65536, WTl+oMW1+(size_t)L*65536,
                                      mb1 + (size_t)L*128, X, stats, N, 4);
    run_bnfin(mg1 + (size_t)L*128, mbe1 + (size_t)L*128, Sl(ST));
    run_gemm1(X, Sl(ST), oMW2 + (size_t)L*16384, mb2 + (size_t)L*128, X);  // in-place
    run_bnfin(mg2 + (size_t)L*128, mbe2 + (size_t)L*128, Sl(SX));
  }

  // ---- Set2Set (6 steps) ----
  zero_k<<<(G*256+255)/256,256,0,stream>>>(qstar, G*256);
  zero_k<<<(G*128+255)/256,256,0,stream>>>(hbuf, G*128);
  zero_k<<<(G*128+255)/256,256,0,stream>>>(cbuf, G*128);
  int dgrid = (N + 3)/4;
  for (int s=0;s<6;++s){
    lstm_step<<<64,256,0,stream>>>(qstar, hbuf, cbuf, P(54), P(55), P(56), P(57), G);
    dot_h_hf<<<dgrid,256,0,stream>>>(X, Sl(SX), hbuf, batch, ebuf, N);
    seg_reduce<<<G,256,0,stream>>>(ebuf, goff, emax, invden, G);
    r_kernel_hf<<<G,128,0,stream>>>(X, Sl(SX), ebuf, goff, emax, invden, qstar, G);
  }

  final_k<<<G,128,0,stream>>>(qstar, P(58), P(59), P(60), P(61), (float*)d_out, G);
}

// Round 6
// 12278.513 us; speedup vs baseline: 1.5456x; 1.5456x over previous
//
#include <hip/hip_runtime.h>
#include <math.h>

// ---------------------------------------------------------------------------
// NetGIN forward on MI355X — round 6: register-streaming MFMA GEMM
// (round 5 with the C-store coverage bug fixed: full 16-chunk-per-row store).
// Activations RAW (pre-BN) fp16 in ws; S = {scale[128], shift[128]} fp32
// applies BN+ReLU on read. GEMM: X rows global->reg, bn+relu+bf16 hi/lo
// split in-reg; W^T hi/lo planes (pre-split, K-major) global->reg (L2-hot);
// 3 MFMA per tile (hi*hi + lo*hi + hi*lo), fp32 acc. No barriers in K-loop.
// Epilogue: +bias, fp16 round, LDS transpose -> full-line store, BN stats
// via shfl reduce -> LDS -> 8-replica global atomics.
// ---------------------------------------------------------------------------

#define DEV_INLINE __device__ __forceinline__
typedef unsigned short u16;

union F16U { _Float16 h; u16 u; };
DEV_INLINE float h2f(u16 v){ F16U t; t.u = v; return (float)t.h; }
DEV_INLINE u16 f2h(float f){ F16U t; t.h = (_Float16)f; return t.u; }
DEV_INLINE float bf2f(u16 h){ return __uint_as_float(((unsigned)h)<<16); }
DEV_INLINE u16 f2bf(float f){
  unsigned u = __float_as_uint(f);
  unsigned r = (u + 0x7FFFu + ((u>>16)&1u)) >> 16;
  return (u16)r;
}
DEV_INLINE float sigmoidf_(float x){ return 1.0f/(1.0f+expf(-x)); }
struct __align__(4) us2 { u16 x, y; };
struct __align__(8) us4 { u16 x, y, z, w; };

typedef __attribute__((ext_vector_type(8))) short s8v;   // 8 bf16/fp16 (4 VGPRs)
typedef __attribute__((ext_vector_type(4))) float f4v;   // 4 fp32 acc

// ---------------- utility ----------------
__global__ void zero_k(float* __restrict__ p, int n){
  int i = blockIdx.x*256 + threadIdx.x;
  if (i < n) p[i] = 0.f;
}

// ---------------- weight pre-transpose + bf16 split ----------------
// src: [count][K][128] fp32 row-major.  dst planes: [count][128][K] (n-major).
__global__ __launch_bounds__(256) void split_transpose(
  const float* __restrict__ src, u16* __restrict__ dh, u16* __restrict__ dl,
  int K, int count)
{
  int tot = count*K*128;
  for (int i = blockIdx.x*256 + threadIdx.x; i < tot; i += gridDim.x*256){
    int k = i % K;
    int n = (i / K) & 127;
    int c = i / (K*128);
    float w = src[(size_t)c*K*128 + (size_t)k*128 + n];
    u16 hi = f2bf(w);
    u16 lo = f2bf(w - bf2f(hi));
    dh[i] = hi; dl[i] = lo;
  }
}

// ---------------- CSR build ----------------
__global__ void count_deg(const int* __restrict__ dst, int* __restrict__ cnt, int E){
  int e = blockIdx.x*256 + threadIdx.x;
  if (e < E) atomicAdd(&cnt[dst[e]], 1);
}

__global__ void scan_excl(const int* __restrict__ cnt, int* __restrict__ offs, int N){
  const int* c = cnt + (size_t)blockIdx.x * N;
  int* o = offs + (size_t)blockIdx.x * (N+1);
  __shared__ int ps[1024];
  int t = threadIdx.x;
  int chunk = (N + 1023) >> 10;
  int lo = t*chunk, hi = min(lo+chunk, N);
  int s = 0;
  for (int i=lo;i<hi;++i) s += c[i];
  ps[t] = s; __syncthreads();
  for (int d=1; d<1024; d<<=1){
    int v = (t>=d) ? ps[t-d] : 0;
    __syncthreads();
    ps[t] += v;
    __syncthreads();
  }
  int pre = (t==0) ? 0 : ps[t-1];
  for (int i=lo;i<hi;++i){ o[i]=pre; pre += c[i]; }
  if (t==1023) o[N] = ps[1023];
}

__global__ void fill_csr(const int* __restrict__ src, const int* __restrict__ dst,
                         const int* __restrict__ offs, int* __restrict__ cur,
                         int* __restrict__ out, int E){
  int e = blockIdx.x*256 + threadIdx.x;
  if (e >= E) return;
  int d = dst[e];
  int pos = offs[d] + atomicAdd(&cur[d], 1);
  out[pos] = src[e];
}

__global__ void graph_offsets(const int* __restrict__ batch, int* __restrict__ goff, int N, int G){
  int g = blockIdx.x*blockDim.x + threadIdx.x;
  if (g > G) return;
  int lo=0, hi=N;
  while (lo<hi){ int mid=(lo+hi)>>1; if (batch[mid] < g) lo=mid+1; else hi=mid; }
  goff[g]=lo;
}

// ---------------- BN finalize (8 stat replicas) ----------------
__global__ void bnfin(float* __restrict__ stats, const float* __restrict__ g,
                      const float* __restrict__ be, float* __restrict__ S, float invN){
  int c = threadIdx.x;   // 128
  float s1 = 0.f, s2 = 0.f;
  #pragma unroll
  for (int r=0;r<8;++r){
    s1 += stats[r*256 + c];       stats[r*256 + c] = 0.f;
    s2 += stats[r*256 + 128 + c]; stats[r*256 + 128 + c] = 0.f;
  }
  float m = s1*invN;
  float v = s2*invN - m*m;
  float sc = g[c]*rsqrtf(v + 1e-5f);
  S[c] = sc;
  S[128+c] = be[c] - m*sc;
}

// ---------------- register-streaming MFMA GEMM ----------------
// C(N,128) = bnrelu(A)(N,K) @ W(K,128) + bias;  K = npart*128.
// Block 256 thr / 4 waves; wave tile = 32 rows x 128 cols (mt=2, nt=8).
// Fragment layouts (mfma_f32_16x16x32_bf16), verified in R4 (PASS):
//   A-op (=W^T): row n = lane&15, k = 8*(lane>>4)+j   (contig 16 B, K-major)
//   B-op (=X^T): col m = lane&15, k = 8*(lane>>4)+j
//   D:           C[row=lane&15][col n=(lane>>4)*4+reg]
__global__ __launch_bounds__(256, 2) void gemm_rs(
  const u16* __restrict__ A0, const u16* __restrict__ A1,
  const u16* __restrict__ A2, const u16* __restrict__ A3,
  const float* __restrict__ S0, const float* __restrict__ S1,
  const float* __restrict__ S2, const float* __restrict__ S3,
  const u16* __restrict__ wt_hi, const u16* __restrict__ wt_lo,
  const float* __restrict__ bias,
  u16* __restrict__ C, float* __restrict__ stats,
  int N, int npart)
{
  __shared__ u16 cst[4][2][16*136];   // per-wave C transpose slices (pad 136)
  __shared__ float sst[256];          // block-level stats accumulator
  const int t = threadIdx.x;
  const int lane = t & 63;
  const int wid = t >> 6;
  const int m16 = lane & 15;
  const int kg = lane >> 4;
  const int wrow0 = blockIdx.x*128 + wid*32;
  const int K = npart << 7;

  sst[t] = 0.f;                       // visible after the pre-epilogue barrier

  f4v acc[2][8];
  #pragma unroll
  for (int i=0;i<2;++i)
    #pragma unroll
    for (int j=0;j<8;++j) acc[i][j] = (f4v){0.f,0.f,0.f,0.f};

  const u16* Ap[4] = {A0,A1,A2,A3};
  const float* Sp[4] = {S0,S1,S2,S3};

  for (int part=0; part<npart; ++part){
    const u16* A = Ap[part];
    const float* S = Sp[part];

    // ---- X fragments: global->reg, bn+relu, bf16 hi/lo split ----
    s8v xh[2][4], xl[2][4];
    #pragma unroll
    for (int mt=0; mt<2; ++mt){
      int row = wrow0 + mt*16 + m16;
      const u16* Arow = A + (size_t)row*128;
      #pragma unroll
      for (int ks=0; ks<4; ++ks){
        int koff = ks*32 + kg*8;
        s8v xr = (row < N) ? *(const s8v*)(Arow + koff)
                           : (s8v){0,0,0,0,0,0,0,0};
        float sc[8], sh[8];
        if (S){
          float4 a0 = *(const float4*)(S + koff);
          float4 a1 = *(const float4*)(S + koff + 4);
          float4 b0 = *(const float4*)(S + 128 + koff);
          float4 b1 = *(const float4*)(S + 128 + koff + 4);
          sc[0]=a0.x; sc[1]=a0.y; sc[2]=a0.z; sc[3]=a0.w;
          sc[4]=a1.x; sc[5]=a1.y; sc[6]=a1.z; sc[7]=a1.w;
          sh[0]=b0.x; sh[1]=b0.y; sh[2]=b0.z; sh[3]=b0.w;
          sh[4]=b1.x; sh[5]=b1.y; sh[6]=b1.z; sh[7]=b1.w;
        }
        s8v h, l;
        #pragma unroll
        for (int j=0;j<8;++j){
          float f = h2f((u16)xr[j]);
          if (S) f = fmaxf(fmaf(f, sc[j], sh[j]), 0.f);
          u16 hb = f2bf(f);
          u16 lb = f2bf(f - bf2f(hb));
          h[j] = (short)hb; l[j] = (short)lb;
        }
        xh[mt][ks] = h; xl[mt][ks] = l;
      }
    }

    // ---- K loop: W fragments global->reg (L2-hot), MFMA ----
    const u16* WHp = wt_hi + part*128;
    const u16* WLp = wt_lo + part*128;
    #pragma unroll
    for (int ks=0; ks<4; ++ks){
      int koff = ks*32 + kg*8;
      #pragma unroll
      for (int nh=0; nh<2; ++nh){
        s8v wh[4], wl[4];
        #pragma unroll
        for (int n4=0;n4<4;++n4){
          int n = (nh*4+n4)*16 + m16;
          size_t wa = (size_t)n*K + koff;
          wh[n4] = *(const s8v*)(WHp + wa);
          wl[n4] = *(const s8v*)(WLp + wa);
        }
        #pragma unroll
        for (int mt=0;mt<2;++mt){
          #pragma unroll
          for (int n4=0;n4<4;++n4){
            acc[mt][nh*4+n4] = __builtin_amdgcn_mfma_f32_16x16x32_bf16(wh[n4], xh[mt][ks], acc[mt][nh*4+n4], 0,0,0);
            acc[mt][nh*4+n4] = __builtin_amdgcn_mfma_f32_16x16x32_bf16(wl[n4], xh[mt][ks], acc[mt][nh*4+n4], 0,0,0);
            acc[mt][nh*4+n4] = __builtin_amdgcn_mfma_f32_16x16x32_bf16(wh[n4], xl[mt][ks], acc[mt][nh*4+n4], 0,0,0);
          }
        }
      }
    }
  }

  __syncthreads();   // sst zeroing visible to all waves

  // ---- epilogue: +bias, fp16 round, stats, LDS transpose ----
  #pragma unroll
  for (int mt=0;mt<2;++mt){
    int row = wrow0 + mt*16 + m16;
    #pragma unroll
    for (int nt=0;nt<8;++nt){
      int n0 = nt*16 + kg*4;
      float4 b4 = *(const float4*)(bias + n0);
      us4 o;
      o.x = f2h(acc[mt][nt][0] + b4.x);
      o.y = f2h(acc[mt][nt][1] + b4.y);
      o.z = f2h(acc[mt][nt][2] + b4.z);
      o.w = f2h(acc[mt][nt][3] + b4.w);
      *(us4*)(&cst[wid][mt][m16*136 + n0]) = o;
      float r0,r1,r2,r3;
      if (row < N){ r0=h2f(o.x); r1=h2f(o.y); r2=h2f(o.z); r3=h2f(o.w); }
      else        { r0=r1=r2=r3=0.f; }
      float s1a=r0, s1b=r1, s1c=r2, s1d=r3;
      float s2a=r0*r0, s2b=r1*r1, s2c=r2*r2, s2d=r3*r3;
      #pragma unroll
      for (int off=1; off<16; off<<=1){
        s1a += __shfl_xor(s1a, off, 64); s1b += __shfl_xor(s1b, off, 64);
        s1c += __shfl_xor(s1c, off, 64); s1d += __shfl_xor(s1d, off, 64);
        s2a += __shfl_xor(s2a, off, 64); s2b += __shfl_xor(s2b, off, 64);
        s2c += __shfl_xor(s2c, off, 64); s2d += __shfl_xor(s2d, off, 64);
      }
      if (m16 == 0){
        atomicAdd(&sst[n0+0], s1a); atomicAdd(&sst[n0+1], s1b);
        atomicAdd(&sst[n0+2], s1c); atomicAdd(&sst[n0+3], s1d);
        atomicAdd(&sst[128+n0+0], s2a); atomicAdd(&sst[128+n0+1], s2b);
        atomicAdd(&sst[128+n0+2], s2c); atomicAdd(&sst[128+n0+3], s2d);
      }
    }
  }
  // full-line C stores from the per-wave LDS slice.
  // FIX (R5 bug): cover ALL 16 16-byte chunks per 256 B row.
  // idx = it*64+lane: r = idx>>4 (row 0..15), c8 = (idx&15)*8 (elem offset).
  // Lanes 0..15 cover one full row contiguously -> coalesced 1 KB per op.
  #pragma unroll
  for (int mt=0;mt<2;++mt){
    #pragma unroll
    for (int it=0; it<4; ++it){
      int idx = it*64 + lane;
      int r = idx >> 4;
      int c8 = (idx & 15) * 8;
      int row = wrow0 + mt*16 + r;
      if (row < N){
        s8v v = *(const s8v*)(&cst[wid][mt][r*136 + c8]);
        *(s8v*)(C + (size_t)row*128 + c8) = v;
      }
    }
  }
  __syncthreads();   // all sst atomics done
  atomicAdd(&stats[((blockIdx.x & 7) << 8) + t], sst[t]);
}

// ---------------- small-K encoder GEMM (fp32 inputs, K <= 26) ----------------
__global__ __launch_bounds__(256) void gemm_enc(
  const float* __restrict__ X0, int w0, const float* __restrict__ X1, int w1,
  const float* __restrict__ W, const float* __restrict__ bias,
  u16* __restrict__ C, float* __restrict__ stats, int N)
{
  __shared__ float Ws[26*128];
  __shared__ float red[256];
  int K = w0 + w1;
  int t = threadIdx.x;
  for (int i=t;i<K*128;i+=256) Ws[i] = W[i];
  __syncthreads();
  int c = t & 127, rh = t >> 7;
  float b = bias[c];
  float s1=0.f, s2=0.f;
  for (int r0 = blockIdx.x*2; r0 < N; r0 += gridDim.x*2){
    int r = r0 + rh;
    if (r < N){
      float acc = b;
      for (int k=0;k<w0;++k) acc = fmaf(X0[(size_t)r*w0+k], Ws[k*128+c], acc);
      for (int k=0;k<w1;++k) acc = fmaf(X1[(size_t)r*w1+k], Ws[(w0+k)*128+c], acc);
      u16 o = f2h(acc);
      C[(size_t)r*128+c] = o;
      float rv = h2f(o);
      s1 += rv; s2 += rv*rv;
    }
  }
  red[t] = s1; __syncthreads();
  if (t < 128) atomicAdd(&stats[t], red[t] + red[t+128]);
  __syncthreads();
  red[t] = s2; __syncthreads();
  if (t < 128) atomicAdd(&stats[128+t], red[t] + red[t+128]);
}

// ---------------- GIN aggregation ----------------
__global__ __launch_bounds__(256) void aggregate_hf(
  const u16* __restrict__ X, const float* __restrict__ S,
  const int* __restrict__ srcs, const int* __restrict__ offs,
  const float* __restrict__ geps, int gi, u16* __restrict__ Z, int N)
{
  int i = blockIdx.x*4 + (threadIdx.x>>6);
  int ln = threadIdx.x & 63;
  int c = ln*2;
  if (i >= N) return;
  float sca = S[c], sha = S[128+c];
  float scb = S[c+1], shb = S[128+c+1];
  float eps1 = 1.0f + geps[gi];
  us2 x0 = *(const us2*)(X + (size_t)i*128 + c);
  float acca = eps1 * fmaxf(fmaf(h2f(x0.x), sca, sha), 0.f);
  float accb = eps1 * fmaxf(fmaf(h2f(x0.y), scb, shb), 0.f);
  int e0 = offs[i], e1 = offs[i+1];
  for (int e=e0; e<e1; ++e){
    int s = srcs[e];
    us2 xv = *(const us2*)(X + (size_t)s*128 + c);
    acca += fmaxf(fmaf(h2f(xv.x), sca, sha), 0.f);
    accb += fmaxf(fmaf(h2f(xv.y), scb, shb), 0.f);
  }
  us2 o; o.x = f2h(acca); o.y = f2h(accb);
  *(us2*)(Z + (size_t)i*128 + c) = o;
}

// ---------------- Set2Set ----------------
__global__ __launch_bounds__(256) void lstm_step(
  float* __restrict__ q_star, float* __restrict__ h, float* __restrict__ cst,
  const float* __restrict__ Wih, const float* __restrict__ Whh,
  const float* __restrict__ bih, const float* __restrict__ bhh, int G)
{
  __shared__ float q[256], hh[128], z[512];
  int t = threadIdx.x;
  for (int g = blockIdx.x; g < G; g += gridDim.x){
    q[t] = q_star[(size_t)g*256 + t];
    if (t < 128) hh[t] = h[(size_t)g*128 + t];
    __syncthreads();
    #pragma unroll
    for (int p=0;p<2;++p){
      int j = t + 256*p;
      float acc = bih[j] + bhh[j];
      const float* wi = Wih + (size_t)j*256;
      const float* wh = Whh + (size_t)j*128;
      for (int k=0;k<256;++k) acc = fmaf(q[k], wi[k], acc);
      for (int k=0;k<128;++k) acc = fmaf(hh[k], wh[k], acc);
      z[j] = acc;
    }
    __syncthreads();
    if (t < 128){
      float i_ = z[t], f_ = z[128+t], g_ = z[256+t], o_ = z[384+t];
      float cc = sigmoidf_(f_)*cst[(size_t)g*128+t] + sigmoidf_(i_)*tanhf(g_);
      float hn = sigmoidf_(o_)*tanhf(cc);
      cst[(size_t)g*128+t] = cc;
      h[(size_t)g*128+t]  = hn;
      q_star[(size_t)g*256+t] = hn;
    }
    __syncthreads();
  }
}

__global__ __launch_bounds__(256) void dot_h_hf(
  const u16* __restrict__ X, const float* __restrict__ S,
  const float* __restrict__ h, const int* __restrict__ batch,
  float* __restrict__ e, int N)
{
  int wv = threadIdx.x >> 6, ln = threadIdx.x & 63;
  int i = blockIdx.x*4 + wv;
  if (i >= N) return;
  int g = batch[i];
  int c = ln*2;
  us2 x2 = *(const us2*)(X + (size_t)i*128 + c);
  float2 h2 = *(const float2*)(h + (size_t)g*128 + c);
  float xa = fmaxf(fmaf(h2f(x2.x), S[c],   S[128+c]),   0.f);
  float xb = fmaxf(fmaf(h2f(x2.y), S[c+1], S[128+c+1]), 0.f);
  float p = xa*h2.x + xb*h2.y;
  #pragma unroll
  for (int off=32; off; off>>=1) p += __shfl_down(p, off, 64);
  if (ln==0) e[i] = p;
}

__global__ __launch_bounds__(256) void seg_reduce(
  const float* __restrict__ e, const int* __restrict__ goff,
  float* __restrict__ emax, float* __restrict__ invden, int G)
{
  int g = blockIdx.x;
  int lo = goff[g], hi = goff[g+1];
  int t = threadIdx.x;
  __shared__ float red[256];
  float m = -3.4e38f;
  for (int i=lo+t; i<hi; i+=256) m = fmaxf(m, e[i]);
  red[t] = m; __syncthreads();
  for (int d=128; d; d>>=1){ if (t<d) red[t] = fmaxf(red[t], red[t+d]); __syncthreads(); }
  m = red[0]; __syncthreads();
  float s = 0.f;
  for (int i=lo+t; i<hi; i+=256) s += expf(e[i]-m);
  red[t] = s; __syncthreads();
  for (int d=128; d; d>>=1){ if (t<d) red[t] += red[t+d]; __syncthreads(); }
  if (t==0){
    emax[g] = m;
    invden[g] = (hi>lo && red[0]>0.f) ? 1.f/red[0] : 0.f;
  }
}

__global__ __launch_bounds__(128) void r_kernel_hf(
  const u16* __restrict__ X, const float* __restrict__ S,
  const float* __restrict__ e, const int* __restrict__ goff,
  const float* __restrict__ emax, const float* __restrict__ invden,
  float* __restrict__ q_star, int G)
{
  int g = blockIdx.x, c = threadIdx.x;
  int lo = goff[g], hi = goff[g+1];
  float m = emax[g], inv = invden[g];
  float sc = S[c], sh = S[128+c];
  float r = 0.f;
  for (int i=lo; i<hi; ++i){
    float w = expf(e[i]-m);
    r = fmaf(w, fmaxf(fmaf(h2f(X[(size_t)i*128+c]), sc, sh), 0.f), r);
  }
  q_star[(size_t)g*256 + 128 + c] = r*inv;
}

__global__ __launch_bounds__(128) void final_k(
  const float* __restrict__ q_star, const float* __restrict__ fc1W,
  const float* __restrict__ fc1b, const float* __restrict__ fc4W,
  const float* __restrict__ fc4b, float* __restrict__ out, int G)
{
  __shared__ float q[256];
  __shared__ float h1[128];
  int g = blockIdx.x, t = threadIdx.x;
  q[t]     = q_star[(size_t)g*256 + t];
  q[128+t] = q_star[(size_t)g*256 + 128 + t];
  __syncthreads();
  float acc = fc1b[t];
  for (int k=0;k<256;++k) acc = fmaf(q[k], fc1W[(size_t)k*128+t], acc);
  h1[t] = fmaxf(acc, 0.f);
  __syncthreads();
  if (t < 12){
    float o = fc4b[t];
    for (int d=0; d<128; ++d) o = fmaf(h1[d], fc4W[(size_t)d*12+t], o);
    out[(size_t)g*12+t] = o;
  }
}

// ---------------------------------------------------------------------------
extern "C" void kernel_launch(void* const* d_in, const int* in_sizes, int n_in,
                              void* d_out, int out_size, void* d_ws, size_t ws_size,
                              hipStream_t stream)
{
  (void)n_in; (void)ws_size;
  const int N = in_sizes[0] / 3;
  const int E = in_sizes[62] / 2;
  const int G = out_size / 12;

  auto P = [&](int i){ return (const float*)d_in[i]; };
  const float* gb1 = P(38); const float* gg1 = P(39); const float* gbe1 = P(40);
  const float* gb2 = P(42); const float* gg2 = P(43); const float* gbe2 = P(44);
  const float* geps = P(45);
  const float* mb1 = P(47); const float* mg1 = P(48); const float* mbe1 = P(49);
  const float* mb2 = P(51); const float* mg2 = P(52); const float* mbe2 = P(53);
  const int* ei[4] = {(const int*)d_in[62], (const int*)d_in[63],
                      (const int*)d_in[64], (const int*)d_in[65]};
  const int* batch = (const int*)d_in[66];

  char* ws = (char*)d_ws;
  size_t off = 0;
  auto alloc = [&](size_t bytes)->char*{
    char* p = ws + off;
    off = (off + bytes + 255) & ~(size_t)255;
    return p;
  };
  u16* X = (u16*)alloc((size_t)N*128*2);              // also the MLP intermediate
  u16* Z[4]; for (int k=0;k<4;++k) Z[k] = (u16*)alloc((size_t)N*128*2);
  float* ebuf  = (float*)alloc((size_t)N*4);
  float* stats = (float*)alloc(8*256*4);              // 8 replicas
  float* Sb    = (float*)alloc(6*256*4);
  int* offs4 = (int*)alloc((size_t)4*(N+1)*4);
  int* srcs4 = (int*)alloc((size_t)4*E*4);
  int* cnt4  = (int*)alloc((size_t)4*N*4);
  int* goff  = (int*)alloc((size_t)(G+1)*4);
  float* qstar = (float*)alloc((size_t)G*256*4);
  float* hbuf  = (float*)alloc((size_t)G*128*4);
  float* cbuf  = (float*)alloc((size_t)G*128*4);
  float* emax  = (float*)alloc((size_t)G*4);
  float* invden= (float*)alloc((size_t)G*4);
  const size_t WT_ELEMS = 1392640;
  u16* WTh = (u16*)alloc(WT_ELEMS*2);
  u16* WTl = (u16*)alloc(WT_ELEMS*2);

  // W^T plane offsets (elems)
  const size_t oEnc0=0, oEnc1=16384, oEnc2=32768, oM0W1=49152, oM0W2=98304;
  const size_t oGW1=114688, oGW2=507904, oMW1=901120, oMW2=1294336;

  const float invN = 1.0f / (float)N;
  const int ST = 0, SX = 1, SZ0 = 2;
  auto Sl = [&](int i){ return Sb + (size_t)i*256; };

  // ---- weight preprocessing (transpose + bf16 split) ----
  auto prep = [&](const float* src, size_t o, int K, int count){
    int tot = count*K*128;
    split_transpose<<<(tot+255)/256,256,0,stream>>>(src, WTh+o, WTl+o, K, count);
  };
  prep(P(9),  oEnc0, 128, 1);
  prep(P(17), oEnc1, 128, 1);
  prep(P(25), oEnc2, 128, 1);
  prep(P(29), oM0W1, 384, 1);
  prep(P(33), oM0W2, 128, 1);
  prep(P(37), oGW1,  128, 24);
  prep(P(41), oGW2,  128, 24);
  prep(P(46), oMW1,  512, 6);
  prep(P(50), oMW2,  128, 6);

  // ---- CSR build ----
  int zgrid = (4*N + 255)/256;
  zero_k<<<zgrid,256,0,stream>>>((float*)cnt4, 4*N);
  int egrid = (E + 255)/256;
  for (int l=0;l<4;++l)
    count_deg<<<egrid,256,0,stream>>>(ei[l]+E, cnt4 + (size_t)l*N, E);
  scan_excl<<<4,1024,0,stream>>>(cnt4, offs4, N);
  zero_k<<<zgrid,256,0,stream>>>((float*)cnt4, 4*N);
  for (int l=0;l<4;++l)
    fill_csr<<<egrid,256,0,stream>>>(ei[l], ei[l]+E, offs4 + (size_t)l*(N+1),
                                     cnt4 + (size_t)l*N, srcs4 + (size_t)l*E, E);
  graph_offsets<<<(G+1+255)/256,256,0,stream>>>(batch, goff, N, G);
  zero_k<<<8,256,0,stream>>>(stats, 8*256);

  int ggrid = (N + 127)/128;
  auto run_bnfin = [&](const float* g, const float* be, float* S){
    bnfin<<<1,128,0,stream>>>(stats, g, be, S, invN);
  };
  auto run_gemm1 = [&](const u16* A, const float* S, size_t wo, const float* b, u16* Cc){
    gemm_rs<<<ggrid,256,0,stream>>>(A,nullptr,nullptr,nullptr, S,nullptr,nullptr,nullptr,
                                    WTh+wo, WTl+wo, b, Cc, stats, N, 1);
  };

  // ---- encoders (X doubles as the intermediate T) ----
  gemm_enc<<<1024,256,0,stream>>>(P(0),3, nullptr,0, P(5), P(6), X, stats, N);
  run_bnfin(P(7), P(8), Sl(ST));
  run_gemm1(X, Sl(ST), oEnc0, P(10), Z[0]);
  run_bnfin(P(11), P(12), Sl(SZ0+0));

  gemm_enc<<<1024,256,0,stream>>>(P(1),13, P(2),13, P(13), P(14), X, stats, N);
  run_bnfin(P(15), P(16), Sl(ST));
  run_gemm1(X, Sl(ST), oEnc1, P(18), Z[1]);
  run_bnfin(P(19), P(20), Sl(SZ0+1));

  gemm_enc<<<1024,256,0,stream>>>(P(3),4, P(4),1, P(21), P(22), X, stats, N);
  run_bnfin(P(23), P(24), Sl(ST));
  run_gemm1(X, Sl(ST), oEnc2, P(26), Z[2]);
  run_bnfin(P(27), P(28), Sl(SZ0+2));

  // m0: concat [nl, na, ea] = Z0,Z1,Z2  (K=384)
  gemm_rs<<<ggrid,256,0,stream>>>(Z[0],Z[1],Z[2],nullptr,
                                  Sl(SZ0+0),Sl(SZ0+1),Sl(SZ0+2),nullptr,
                                  WTh+oM0W1, WTl+oM0W1, P(30), X, stats, N, 3);
  run_bnfin(P(31), P(32), Sl(ST));
  run_gemm1(X, Sl(ST), oM0W2, P(34), X);        // in-place (row-exclusive)
  run_bnfin(P(35), P(36), Sl(SX));

  // ---- 6 GIN layers ----
  int agrid = (N + 3)/4;
  for (int L=0; L<6; ++L){
    for (int k=0;k<4;++k){
      int gi = 4*L + k;
      aggregate_hf<<<agrid,256,0,stream>>>(X, Sl(SX), srcs4 + (size_t)k*E,
                                           offs4 + (size_t)k*(N+1), geps, gi, Z[k], N);
    }
    for (int k=0;k<4;++k){
      int gi = 4*L + k;
      run_gemm1(Z[k], nullptr, oGW1 + (size_t)gi*16384, gb1 + (size_t)gi*128, X);
      run_bnfin(gg1 + (size_t)gi*128, gbe1 + (size_t)gi*128, Sl(ST));
      run_gemm1(X, Sl(ST), oGW2 + (size_t)gi*16384, gb2 + (size_t)gi*128, Z[k]);
      run_bnfin(gg2 + (size_t)gi*128, gbe2 + (size_t)gi*128, Sl(SZ0+k));
    }
    // fusion: concat [x1, x3, x2, x4] = Z0, Z2, Z1, Z3  (K=512)
    gemm_rs<<<ggrid,256,0,stream>>>(Z[0],Z[2],Z[1],Z[3],
                                    Sl(SZ0+0),Sl(SZ0+2),Sl(SZ0+1),Sl(SZ0+3),
                                    WTh+oMW1+(size_t)L*65536, WTl+oMW1+(size_t)L*65536,
                                    mb1 + (size_t)L*128, X, stats, N, 4);
    run_bnfin(mg1 + (size_t)L*128, mbe1 + (size_t)L*128, Sl(ST));
    run_gemm1(X, Sl(ST), oMW2 + (size_t)L*16384, mb2 + (size_t)L*128, X);  // in-place
    run_bnfin(mg2 + (size_t)L*128, mbe2 + (size_t)L*128, Sl(SX));
  }

  // ---- Set2Set (6 steps) ----
  zero_k<<<(G*256+255)/256,256,0,stream>>>(qstar, G*256);
  zero_k<<<(G*128+255)/256,256,0,stream>>>(hbuf, G*128);
  zero_k<<<(G*128+255)/256,256,0,stream>>>(cbuf, G*128);
  int dgrid = (N + 3)/4;
  for (int s=0;s<6;++s){
    lstm_step<<<64,256,0,stream>>>(qstar, hbuf, cbuf, P(54), P(55), P(56), P(57), G);
    dot_h_hf<<<dgrid,256,0,stream>>>(X, Sl(SX), hbuf, batch, ebuf, N);
    seg_reduce<<<G,256,0,stream>>>(ebuf, goff, emax, invden, G);
    r_kernel_hf<<<G,128,0,stream>>>(X, Sl(SX), ebuf, goff, emax, invden, qstar, G);
  }

  final_k<<<G,128,0,stream>>>(qstar, P(58), P(59), P(60), P(61), (float*)d_out, G);
}